// Round 5
// baseline (194.648 us; speedup 1.0000x reference)
//
#include <hip/hip_runtime.h>

// GaussianPooling: fm[512,256,256] f32, keypoints[4096,2] int, out[4096,512] f32.
// 5x5 gaussian sigma=2, separable: k = g(dy)*g(dx)/s^2.
//
// R14 (= R13 + flattened compute):
//  - KEY CHANGE: compute is flattened across all 256 threads. R13 processed
//    the 4 per-wave segments independently: cs ~ 128 < 256 meant threads
//    128..255 (waves 2-3) were IDLE through the whole compute phase and each
//    active lane chewed 4 entries serially (dependent LDS chains). Now the
//    segments are concatenated (prefix over cnt[0..3]); thread t handles
//    global entries t, t+256, (t+512): ~2 entries/thread over all 8 waves/CU.
//    Predicted: per-channel compute wall ~halves if compute-bound.
//  - Decode still happens ONCE (at i==0) into per-thread static arrays
//    (en/exa/elr0/ewx[3][8]); res[3][8] accumulates per channel. All indices
//    compile-time static (no scratch spill).
//  - Kept from R13: block = (strip q, 8 channels), grid 512 = 2 blocks/CU,
//    double-buffered plane with sync -> issue-next-stage -> compute pipeline,
//    LDS-DMA width=16 row staging (per-lane global contiguous, wave-uniform
//    LDS dest), kp scan + ballot-compaction once per block, 32 B contiguous
//    stores, XCD swizzle (paired groups share b&7 -> same XCD for line merge).
//  - Overflow fallback (cnt>CAPW, never taken for this input): wave rescans
//    its kp range and computes rank>=CAPW entries straight from global fm.

#define NC  512
#define NH  256
#define NW  256
#define NKP 4096

#define NSTRIP 8               // y-strips of 32 rows
#define STRIP_SHIFT 5
#define SLICE_ROWS 36          // 32 + 2x2 halo
#define STR 260                // LDS row stride: +4 keeps 16B align, rotates banks
#define PLANE (SLICE_ROWS * STR)
#define CAPW 192               // per-wave list capacity (mean 128, sigma ~11)
#define G 8                    // channels per block
#define NENT 3                 // max entries per thread: ceil(4*CAPW/256)

// ---------------- fused pool ----------------
// b = (p&7) + 8*((p>>3)*16 + q*2 + m), p = channel-pair 0..31, m = member.
// Groups g=2p and g=2p+1 (which share out-lines) share b&7 -> same XCD.
__global__ __launch_bounds__(256) void pool_kernel(
    const float* __restrict__ fm, const int* __restrict__ kp,
    float* __restrict__ out)
{
    __shared__ float    plane[2 * PLANE];          // 74,880 B
    __shared__ unsigned lds_list[4 * CAPW];        //  3,072 B
    __shared__ int      cnt[4];                    //     16 B

    const int b     = blockIdx.x;
    const int x7    = b & 7;
    const int inner = b >> 3;          // 0..63
    const int hi    = inner >> 4;      // p>>3, 0..3
    const int rem   = inner & 15;
    const int q     = rem >> 1;        // 0..7
    const int m     = rem & 1;
    const int p     = (hi << 3) | x7;  // 0..31
    const int gidx  = (p << 1) | m;    // 0..63
    const int c0    = gidx << 3;       // first channel of the group

    const int t    = threadIdx.x;
    const int w    = t >> 6;           // wave 0..3
    const int lane = t & 63;
    const int ybase = (q << STRIP_SHIFT) - 2;
    const unsigned long long lmlt = (1ull << lane) - 1ull;

    // ---- issue the wave's 8 int4 kp loads (1024 kps/wave) FIRST ----
    const int4* kp4 = (const int4*)kp;     // 2 keypoints per int4
    int4 vv[8];
#pragma unroll
    for (int it = 0; it < 8; ++it)
        vv[it] = kp4[(w << 9) + (it << 6) + lane];

    // ---- stage channel c0 into buffer 0 (fire-and-forget) ----
    // wave w stages rows w+4k, k=0..8; 64 lanes x 16 B = one full 1 KB row;
    // LDS dest row*1040 + lane*16 (wave-uniform base, 16B aligned).
#define STAGE(CH, BASE)                                                        \
    do {                                                                       \
        const float* _src = fm + ((size_t)(CH) << 16);                         \
        _Pragma("unroll")                                                      \
        for (int _k = 0; _k < 9; ++_k) {                                       \
            const int _row = w + (_k << 2);                                    \
            const int _gr  = ybase + _row;                                     \
            if ((unsigned)_gr < 256u) {                                        \
                const float* _gp = _src + (_gr << 8) + (lane << 2);            \
                float*       _lp = (BASE) + _row * STR + (lane << 2);          \
                __builtin_amdgcn_global_load_lds(                              \
                    (const __attribute__((address_space(1))) void*)_gp,        \
                    (__attribute__((address_space(3))) void*)_lp, 16, 0, 0);   \
            }                                                                  \
        }                                                                      \
    } while (0)

    STAGE(c0, plane);

    // ---- ballot-compact scan (consumes kp regs -> waits only the kp loads;
    //      staging DMAs keep flying underneath) ----
    int off = 0;
#pragma unroll
    for (int it = 0; it < 8; ++it) {
        const int i0 = (((w << 9) + (it << 6) + lane) << 1);
        {
            const int x = min(max(vv[it].x, 2), NW - 3);
            const int y = min(max(vv[it].y, 2), NH - 3);
            const bool mm = ((y >> STRIP_SHIFT) == q);
            const unsigned long long bal = __ballot(mm);
            const int pos = off + __popcll(bal & lmlt);
            if (mm && pos < CAPW)
                lds_list[w * CAPW + pos] =
                    (unsigned)i0 | ((unsigned)x << 12) | ((unsigned)y << 20);
            off += __popcll(bal);
        }
        {
            const int x = min(max(vv[it].z, 2), NW - 3);
            const int y = min(max(vv[it].w, 2), NH - 3);
            const bool mm = ((y >> STRIP_SHIFT) == q);
            const unsigned long long bal = __ballot(mm);
            const int pos = off + __popcll(bal & lmlt);
            if (mm && pos < CAPW)
                lds_list[w * CAPW + pos] =
                    (unsigned)(i0 + 1) | ((unsigned)x << 12) | ((unsigned)y << 20);
            off += __popcll(bal);
        }
    }
    if (lane == 0) cnt[w] = off;           // full count (may exceed CAPW)

    // gaussian weights
    const float e1 = 0.8824969025845955f;  // exp(-1/8)
    const float e2 = 0.6065306597126334f;  // exp(-4/8)
    const float s  = 2.0f * (e1 + e2) + 1.0f;
    const float inv_s2 = 1.0f / (s * s);
    const float g[5] = {e2, e1, 1.0f, e1, e2};
    float gy[5];
#pragma unroll
    for (int i = 0; i < 5; i++) gy[i] = g[i] * inv_s2;

    // per-thread entry state (decoded once, reused for all 8 channels)
    bool  evd[NENT];
    int   en[NENT], exa[NENT], elr0[NENT];
    float ewx[NENT][8];
    float res[NENT][G];

    // ---- channel pipeline: sync -> issue next stage -> compute current ----
#pragma unroll
    for (int i = 0; i < G; ++i) {
        __syncthreads();   // drains vmcnt: stage(i) complete; lists visible (i==0)

        if (i < G - 1)
            STAGE(c0 + i + 1, plane + ((i + 1) & 1) * PLANE);

        if (i == 0) {
            // flatten the 4 segments; decode this thread's <=3 entries, once
            const int cs0 = min(cnt[0], CAPW);
            const int cs1 = min(cnt[1], CAPW);
            const int cs2 = min(cnt[2], CAPW);
            const int cs3 = min(cnt[3], CAPW);
            const int total = cs0 + cs1 + cs2 + cs3;
#pragma unroll
            for (int k = 0; k < NENT; ++k) {
                const int e = t + (k << 8);
                evd[k] = (e < total);
                en[k] = 0; exa[k] = 0; elr0[k] = 0;
#pragma unroll
                for (int j = 0; j < 8; ++j) ewx[k][j] = 0.0f;
                if (evd[k]) {
                    int idx = e, seg = 0;
                    if (idx >= cs0) { idx -= cs0; seg = 1;
                        if (idx >= cs1) { idx -= cs1; seg = 2;
                            if (idx >= cs2) { idx -= cs2; seg = 3; } } }
                    const unsigned pk = lds_list[seg * CAPW + idx];
                    const int n  = (int)(pk & 0xFFFu);
                    const int xc = (int)((pk >> 12) & 0xFFu);
                    const int yc = (int)((pk >> 20) & 0xFFu);
                    const int x0 = xc - 2;
                    const int r  = x0 & 3;
                    en[k]   = n;
                    exa[k]  = x0 - r;
                    elr0[k] = yc - (q << STRIP_SHIFT);
#pragma unroll
                    for (int j = 0; j < 8; ++j)
                        ewx[k][j] = (j >= r && j < r + 5) ? g[j - r] : 0.0f;
                }
            }
        }

        const float* cur = plane + (i & 1) * PLANE;
#pragma unroll
        for (int k = 0; k < NENT; ++k) {
            if (evd[k]) {
                float acc = 0.0f;
#pragma unroll
                for (int dy = 0; dy < 5; ++dy) {
                    const float* rowp = &cur[(elr0[k] + dy) * STR + exa[k]];
                    float4 a  = *(const float4*)rowp;
                    float4 b4 = *(const float4*)(rowp + 4);
                    acc += gy[dy] * (a.x * ewx[k][0] + a.y * ewx[k][1]
                                   + a.z * ewx[k][2] + a.w * ewx[k][3]
                                   + b4.x * ewx[k][4] + b4.y * ewx[k][5]
                                   + b4.z * ewx[k][6] + b4.w * ewx[k][7]);
                }
                res[k][i] = acc;
            }
        }
    }

    // ---- store: one 32 B contiguous write per entry (two float4) ----
#pragma unroll
    for (int k = 0; k < NENT; ++k) {
        if (evd[k]) {
            float4 s0 = make_float4(res[k][0], res[k][1], res[k][2], res[k][3]);
            float4 s1 = make_float4(res[k][4], res[k][5], res[k][6], res[k][7]);
            float* op = out + (size_t)en[k] * NC + c0;
            *(float4*)op       = s0;
            *((float4*)op + 1) = s1;
        }
    }

    // ---- overflow fallback (cnt[w] > CAPW, wave-uniform; never taken for
    //      this input). Rank >= CAPW entries computed straight from global fm. ----
    if (cnt[w] > CAPW) {
        int off2 = 0;
#pragma unroll 1
        for (int it = 0; it < 8; ++it) {
            const int4 v = kp4[(w << 9) + (it << 6) + lane];
            const int i0 = (((w << 9) + (it << 6) + lane) << 1);
#pragma unroll
            for (int half = 0; half < 2; ++half) {
                const int xr = half ? v.z : v.x;
                const int yr = half ? v.w : v.y;
                const int x = min(max(xr, 2), NW - 3);
                const int y = min(max(yr, 2), NH - 3);
                const bool mm = ((y >> STRIP_SHIFT) == q);
                const unsigned long long bal = __ballot(mm);
                const int pos = off2 + __popcll(bal & lmlt);
                if (mm && pos >= CAPW) {
                    const int x0 = x - 2;
                    const int r  = x0 & 3;
                    const int xa = x0 - r;
                    float wx[8];
#pragma unroll
                    for (int j = 0; j < 8; ++j)
                        wx[j] = (j >= r && j < r + 5) ? g[j - r] : 0.0f;
#pragma unroll 1
                    for (int ch = 0; ch < G; ++ch) {
                        const float* base = fm + (((size_t)(c0 + ch)) << 16)
                                          + (size_t)(y - 2) * NW + xa;
                        float acc = 0.0f;
#pragma unroll
                        for (int dy = 0; dy < 5; ++dy) {
                            const float4* p0 = (const float4*)(base + dy * NW);
                            float4 a = p0[0], b4 = p0[1];
                            acc += gy[dy] * (a.x * wx[0] + a.y * wx[1] + a.z * wx[2]
                                           + a.w * wx[3] + b4.x * wx[4] + b4.y * wx[5]
                                           + b4.z * wx[6] + b4.w * wx[7]);
                        }
                        out[(size_t)(i0 + half) * NC + c0 + ch] = acc;
                    }
                }
                off2 += __popcll(bal);
            }
        }
    }
#undef STAGE
}

// ---------------- fallback (round-1 direct kernel) ----------------
__global__ __launch_bounds__(256) void gpool_direct_kernel(
    const float* __restrict__ fm, const int* __restrict__ kp,
    float* __restrict__ out)
{
    const int n = blockIdx.x;
    const int t = threadIdx.x;

    int x = kp[2 * n + 0];
    int y = kp[2 * n + 1];
    x = min(max(x, 2), NW - 3);
    y = min(max(y, 2), NH - 3);

    const float e1 = 0.8824969025845955f;
    const float e2 = 0.6065306597126334f;
    const float s  = 2.0f * (e1 + e2) + 1.0f;
    const float inv_s2 = 1.0f / (s * s);
    float g[5] = {e2, e1, 1.0f, e1, e2};
    float gy[5];
#pragma unroll
    for (int i = 0; i < 5; i++) gy[i] = g[i] * inv_s2;

    const int x0 = x - 2;
    const int r  = x0 & 3;
    const int xa = x0 - r;
    float wx[8];
#pragma unroll
    for (int i = 0; i < 8; i++)
        wx[i] = (i >= r && i < r + 5) ? g[i - r] : 0.0f;

    const float* base0 = fm + ((size_t)t * NH + (y - 2)) * NW + xa;
    const float* base1 = fm + ((size_t)(t + 256) * NH + (y - 2)) * NW + xa;

    float acc0 = 0.0f, acc1 = 0.0f;
#pragma unroll
    for (int dy = 0; dy < 5; dy++) {
        const float4* p0 = (const float4*)(base0 + dy * NW);
        const float4* p1 = (const float4*)(base1 + dy * NW);
        float4 a0 = p0[0], b0 = p0[1], a1 = p1[0], b1 = p1[1];
        acc0 += gy[dy] * (a0.x * wx[0] + a0.y * wx[1] + a0.z * wx[2] + a0.w * wx[3]
                        + b0.x * wx[4] + b0.y * wx[5] + b0.z * wx[6] + b0.w * wx[7]);
        acc1 += gy[dy] * (a1.x * wx[0] + a1.y * wx[1] + a1.z * wx[2] + a1.w * wx[3]
                        + b1.x * wx[4] + b1.y * wx[5] + b1.z * wx[6] + b1.w * wx[7]);
    }

    out[(size_t)n * NC + t]       = acc0;
    out[(size_t)n * NC + t + 256] = acc1;
}

extern "C" void kernel_launch(void* const* d_in, const int* in_sizes, int n_in,
                              void* d_out, int out_size, void* d_ws, size_t ws_size,
                              hipStream_t stream)
{
    const float* fm  = (const float*)d_in[0];
    const int*   kp  = (const int*)d_in[1];
    float*       out = (float*)d_out;
    const int n_kp   = in_sizes[1] / 2;   // 4096

    (void)d_ws; (void)ws_size;            // workspace-free

    if (n_kp == NKP) {
        pool_kernel<<<NSTRIP * (NC / G), 256, 0, stream>>>(fm, kp, out);
    } else {
        gpool_direct_kernel<<<n_kp, 256, 0, stream>>>(fm, kp, out);
    }
}